// Round 11
// baseline (250.487 us; speedup 1.0000x reference)
//
#include <hip/hip_runtime.h>

#define N_NODES 10000
#define N_EDGES 320000
#define MPAD 10112   // 158 * 64
#define NBIN 10048
#define CHUNK 2048
#define NCH 157      // ceil(E / CHUNK)
#define CAP 128      // fixed CSR row capacity (mean degree 32; 128 is ~17 sigma)
#define PREP_BLOCKS 512
#define PREP_TOT 1148480L

typedef unsigned short u16;
typedef short bf16x8 __attribute__((ext_vector_type(8)));
typedef float f32x4 __attribute__((ext_vector_type(4)));

__device__ __forceinline__ u16 f2b(float f) {
  unsigned u = __builtin_bit_cast(unsigned, f);
  unsigned r = u + 0x7fffu + ((u >> 16) & 1u);
  return (u16)(r >> 16);
}
__device__ __forceinline__ unsigned pack2(float a, float b) {
  return (unsigned)f2b(a) | ((unsigned)f2b(b) << 16);
}
__device__ __forceinline__ float blo(unsigned u) { return __builtin_bit_cast(float, u << 16); }
__device__ __forceinline__ float bhi(unsigned u) { return __builtin_bit_cast(float, u & 0xffff0000u); }

// ---------------------------------------------------------- param struct ----
struct PP {
  const float *x;
  const float *w0, *w1, *w2, *fcw0, *injw0, *fcw1, *injw1, *outw;
  const float *fcb0, *injb0, *fcb1, *injb1, *alpha, *outb;
  u16 *xb, *w0t, *w1t, *w2t, *wc1t, *wft;
  float *bias1, *bf;
};

// ------------------------------------------------------------- edge_hist ----
// Per-chunk PACKED histograms (R in low16, C in high16; chunk=2048 edges so
// no overflow). Separate kernel so prep doesn't inherit the 40KB LDS (R10:
// merged version capped prep blocks at 4 blocks/CU).
__global__ __launch_bounds__(256) void edge_hist(const int* __restrict__ ei,
                                                 unsigned* __restrict__ histRC) {
  __shared__ unsigned sh[NBIN];   // 40.2 KB packed
  const int tid = threadIdx.x, ch = blockIdx.x;
  for (int i = tid; i < NBIN; i += 256) sh[i] = 0;
  __syncthreads();
  const int e0 = ch * CHUNK;
#pragma unroll
  for (int j = 0; j < CHUNK; j += 256) {
    int e = e0 + j + tid;
    if (e < N_EDGES) {
      atomicAdd(&sh[ei[e]], 1u);                 // row (scatter dest)
      atomicAdd(&sh[ei[N_EDGES + e]], 65536u);   // col (deg source)
    }
  }
  __syncthreads();
  for (int i = tid; i < NBIN; i += 256)
    histRC[(size_t)ch * NBIN + i] = sh[i];
}

// ------------------------------------------------------------------ prep ----
// Grid-stride, no LDS: x->bf16 (float4), W^T casts, fused Wcat1, and the
// FC2+out fold Wf = Wcat2 @ out_w with FOUR partial accumulators to break the
// 512-FMA fp32 dependency chain (R10: single-acc chain ~2048 cyc/item was the
// long pole inside prep). Pure function of d_in -> replay-safe.
__global__ __launch_bounds__(256) void prep(PP P) {
  const float alpha = P.alpha[0];
  const long stride = (long)PREP_BLOCKS * 256;
  for (long ii = (long)blockIdx.x * 256 + threadIdx.x; ii < PREP_TOT; ii += stride) {
    long i = ii;
    if (i < 640000L) {  // x -> bf16, 4 floats per item
      float4 v = ((const float4*)P.x)[i];
      uint2 o;
      o.x = pack2(v.x, v.y);
      o.y = pack2(v.z, v.w);
      *(uint2*)(P.xb + 4 * i) = o;
      continue;
    }
    i -= 640000L;
    if (i < 65536) { P.w0t[i] = f2b(P.w0[(i & 255) * 256 + (i >> 8)]); continue; }
    i -= 65536;
    if (i < 65536) { P.w1t[i] = f2b(P.w1[(i & 255) * 256 + (i >> 8)]); continue; }
    i -= 65536;
    if (i < 65536) { P.w2t[i] = f2b(P.w2[(i & 255) * 256 + (i >> 8)]); continue; }
    i -= 65536;
    if (i < 262144) {  // Wcat1^T [512 n][512 k]: k<256 -> alpha*fc_w0 ; else inj_w0
      int n = (int)(i >> 9), k = (int)(i & 511);
      float v = (k < 256) ? alpha * P.fcw0[k * 512 + n] : P.injw0[(k - 256) * 512 + n];
      P.wc1t[i] = f2b(v); continue;
    }
    i -= 262144;
    if (i < 49152) {   // Wf^T [64 n][768 k] = (Wcat2 @ out_w)^T
      int n = (int)(i & 63), k = (int)(i >> 6);
      const float* fr = (k < 512) ? P.fcw1 + (size_t)k * 512
                                  : P.injw1 + (size_t)(k - 512) * 512;
      float a0 = 0.f, a1 = 0.f, a2 = 0.f, a3 = 0.f;
#pragma unroll 4
      for (int j = 0; j < 512; j += 4) {
        float4 f = *(const float4*)(fr + j);
        a0 += f.x * P.outw[(j + 0) * 64 + n];
        a1 += f.y * P.outw[(j + 1) * 64 + n];
        a2 += f.z * P.outw[(j + 2) * 64 + n];
        a3 += f.w * P.outw[(j + 3) * 64 + n];
      }
      float acc = (a0 + a1) + (a2 + a3);
      if (k < 512) acc *= alpha;
      P.wft[n * 768 + k] = f2b(acc);
      continue;
    }
    i -= 49152;
    if (i < 64) {      // bf = bias2 @ out_w + out_b (bias2 = alpha*fcb1+injb1)
      float acc = P.outb[i];
#pragma unroll 8
      for (int j = 0; j < 512; ++j)
        acc += (alpha * P.fcb1[j] + P.injb1[j]) * P.outw[j * 64 + i];
      P.bf[i] = acc;
      continue;
    }
    i -= 64;
    if (i < 512) { P.bias1[i] = alpha * P.fcb0[i] + P.injb0[i]; continue; }
  }
}

// ----------------------------------------------------------- CSR build ------
// Fixed-capacity CSR (row r = [r*CAP, r*CAP+cnt[r])) -> no global scan.
__global__ __launch_bounds__(64) void col_scan(const unsigned* __restrict__ histRC,
                                               u16* __restrict__ chunkoff,
                                               int* __restrict__ cnt,
                                               float* __restrict__ deg_inv) {
  int r = blockIdx.x * 64 + threadIdx.x;
  if (r >= MPAD) return;
  if (r >= NBIN) { deg_inv[r] = 1.0f; return; }
  unsigned run = 0;
#pragma unroll 8
  for (int ch = 0; ch < NCH; ++ch) {
    chunkoff[(size_t)ch * NBIN + r] = (u16)(run & 0xffffu);
    run += histRC[(size_t)ch * NBIN + r];
  }
  int cr = (int)(run & 0xffffu);
  int dg = (int)(run >> 16);
  cnt[r] = cr;
  deg_inv[r] = 1.0f / (float)(dg > 1 ? dg : 1);
}

// placement: LDS cursor seeded from chunkoff (global state untouched ->
// replay-safe). rank guard prevents OOB if CAP were ever violated.
__global__ __launch_bounds__(256) void place_edges(const int* __restrict__ ei,
                                                   const u16* __restrict__ chunkoff,
                                                   int* __restrict__ csr) {
  __shared__ int cur[NBIN];   // 40 KB
  const int ch = blockIdx.x, t = threadIdx.x;
  const u16* co = chunkoff + (size_t)ch * NBIN;
  for (int i = t; i < NBIN; i += 256) cur[i] = co[i];
  __syncthreads();
  const int e0 = ch * CHUNK;
#pragma unroll
  for (int j = 0; j < CHUNK; j += 256) {
    int e = e0 + j + t;
    if (e < N_EDGES) {
      int r = ei[e];
      int c = ei[N_EDGES + e];
      int rank = atomicAdd(&cur[r], 1);   // LDS only; disjoint slots across chunks
      if (rank < CAP) csr[r * CAP + rank] = c;
    }
  }
}

// ---------------------------------------------------------------- GEMM ------
// 64x64 tile, TWO waves per block (128 threads): each wave computes 32x64
// (2x4 MFMA 16x16x32 frags). Proven R7/R9/R10 config (~8 blocks/CU resident).
template<int K, bool RELU, bool SCALE, bool F32OUT>
__global__ __launch_bounds__(128) void gemm64(
    const u16* __restrict__ A, int lda,
    const u16* __restrict__ Bt,
    const float* __restrict__ bias,
    const float* __restrict__ scale,
    u16* __restrict__ Cb, float* __restrict__ Cf, int ldc)
{
  __shared__ u16 As[64 * 72];
  __shared__ u16 Bs[64 * 72];
  const int tid = threadIdx.x;
  const int m0 = blockIdx.x * 64;
  const int n0 = blockIdx.y * 64;
  const int wave = tid >> 6;
  const int lane = tid & 63;
  const int wr = wave * 32;
  const int lm = lane & 15;
  const int koff = (lane >> 4) * 8;

  const int srow = tid >> 2;          // stages rows srow and srow+32
  const int scol = (tid & 3) * 16;    // 16 u16 per row = 2 int4
  const u16* Ag0 = A + (size_t)(m0 + srow) * lda + scol;
  const u16* Ag1 = A + (size_t)(m0 + srow + 32) * lda + scol;
  const u16* Bg0 = Bt + (size_t)(n0 + srow) * K + scol;
  const u16* Bg1 = Bt + (size_t)(n0 + srow + 32) * K + scol;
  u16* Asw0 = &As[srow * 72 + scol];
  u16* Asw1 = &As[(srow + 32) * 72 + scol];
  u16* Bsw0 = &Bs[srow * 72 + scol];
  u16* Bsw1 = &Bs[(srow + 32) * 72 + scol];

  f32x4 acc[2][4] = {};

  int4 pa0 = *(const int4*)(Ag0),     pa1 = *(const int4*)(Ag0 + 8);
  int4 pa2 = *(const int4*)(Ag1),     pa3 = *(const int4*)(Ag1 + 8);
  int4 pb0 = *(const int4*)(Bg0),     pb1 = *(const int4*)(Bg0 + 8);
  int4 pb2 = *(const int4*)(Bg1),     pb3 = *(const int4*)(Bg1 + 8);

#pragma unroll
  for (int kb = 0; kb < K; kb += 64) {
    __syncthreads();
    *(int4*)Asw0 = pa0; *(int4*)(Asw0 + 8) = pa1;
    *(int4*)Asw1 = pa2; *(int4*)(Asw1 + 8) = pa3;
    *(int4*)Bsw0 = pb0; *(int4*)(Bsw0 + 8) = pb1;
    *(int4*)Bsw1 = pb2; *(int4*)(Bsw1 + 8) = pb3;
    __syncthreads();
    if (kb + 64 < K) {
      pa0 = *(const int4*)(Ag0 + kb + 64); pa1 = *(const int4*)(Ag0 + kb + 72);
      pa2 = *(const int4*)(Ag1 + kb + 64); pa3 = *(const int4*)(Ag1 + kb + 72);
      pb0 = *(const int4*)(Bg0 + kb + 64); pb1 = *(const int4*)(Bg0 + kb + 72);
      pb2 = *(const int4*)(Bg1 + kb + 64); pb3 = *(const int4*)(Bg1 + kb + 72);
    }
#pragma unroll
    for (int ks = 0; ks < 2; ++ks) {
      bf16x8 af[2], bf[4];
#pragma unroll
      for (int mi = 0; mi < 2; ++mi)
        af[mi] = *(const bf16x8*)&As[(wr + mi * 16 + lm) * 72 + ks * 32 + koff];
#pragma unroll
      for (int ni = 0; ni < 4; ++ni)
        bf[ni] = *(const bf16x8*)&Bs[(ni * 16 + lm) * 72 + ks * 32 + koff];
#pragma unroll
      for (int mi = 0; mi < 2; ++mi)
#pragma unroll
        for (int ni = 0; ni < 4; ++ni)
          acc[mi][ni] = __builtin_amdgcn_mfma_f32_16x16x32_bf16(af[mi], bf[ni], acc[mi][ni], 0, 0, 0);
    }
  }

  const int q4 = (lane >> 4) * 4;
#pragma unroll
  for (int mi = 0; mi < 2; ++mi) {
#pragma unroll
    for (int ni = 0; ni < 4; ++ni) {
      const int gc = n0 + ni * 16 + lm;
      const float bv = bias[gc];
#pragma unroll
      for (int r = 0; r < 4; ++r) {
        const int gr = m0 + wr + mi * 16 + q4 + r;
        float v = acc[mi][ni][r] + bv;
        if (RELU) v = fmaxf(v, 0.f);
        if (SCALE) v *= scale[gr];
        if (F32OUT) {
          if (gr < N_NODES) Cf[(size_t)gr * ldc + gc] = v;
        } else {
          Cb[(size_t)gr * ldc + gc] = f2b(v);
        }
      }
    }
  }
}

// ----------------------------------------------------------- aggregate ------
// One WAVE per node; paired gather: half-wave per neighbor, uint4/lane.
// Main loop now 16 neighbors/iter (8 loads in flight per lane; typical row
// deg~32 -> 2 wide iterations), then 8, then tail. Cross-half __shfl reduce.
__global__ __launch_bounds__(256) void aggregate(
    const u16* __restrict__ tmp, const int* __restrict__ cnt,
    const int* __restrict__ csr, u16* __restrict__ out0,
    u16* __restrict__ A1, u16* __restrict__ A2, int mode)
{
  const int wv = threadIdx.x >> 6;
  const int lane = threadIdx.x & 63;
  const int r = blockIdx.x * 4 + wv;          // grid = 2500 -> r in [0,10000)
  const int half = lane >> 5;
  const int q = lane & 31;
  const int beg = r * CAP, end = beg + cnt[r];
  const size_t feat = (size_t)q * 16;
  const char* tb = (const char*)tmp;

  float s0 = 0.f, s1 = 0.f, s2 = 0.f, s3 = 0.f, s4 = 0.f, s5 = 0.f, s6 = 0.f, s7 = 0.f;
  int i = beg;
  for (; i + 16 <= end; i += 16) {
    uint4 v[8];
#pragma unroll
    for (int j = 0; j < 8; ++j)
      v[j] = *(const uint4*)(tb + (size_t)csr[i + 2 * j + half] * 512 + feat);
#pragma unroll
    for (int j = 0; j < 8; ++j) {
      s0 += blo(v[j].x); s1 += bhi(v[j].x); s2 += blo(v[j].y); s3 += bhi(v[j].y);
      s4 += blo(v[j].z); s5 += bhi(v[j].z); s6 += blo(v[j].w); s7 += bhi(v[j].w);
    }
  }
  for (; i + 8 <= end; i += 8) {
    uint4 v[4];
#pragma unroll
    for (int j = 0; j < 4; ++j)
      v[j] = *(const uint4*)(tb + (size_t)csr[i + 2 * j + half] * 512 + feat);
#pragma unroll
    for (int j = 0; j < 4; ++j) {
      s0 += blo(v[j].x); s1 += bhi(v[j].x); s2 += blo(v[j].y); s3 += bhi(v[j].y);
      s4 += blo(v[j].z); s5 += bhi(v[j].z); s6 += blo(v[j].w); s7 += bhi(v[j].w);
    }
  }
  for (; i < end; i += 2) {
    int id = i + half;
    if (id < end) {
      uint4 v = *(const uint4*)(tb + (size_t)csr[id] * 512 + feat);
      s0 += blo(v.x); s1 += bhi(v.x); s2 += blo(v.y); s3 += bhi(v.y);
      s4 += blo(v.z); s5 += bhi(v.z); s6 += blo(v.w); s7 += bhi(v.w);
    }
  }
  const int src = lane ^ 32;
  s0 += __shfl(s0, src, 64); s1 += __shfl(s1, src, 64);
  s2 += __shfl(s2, src, 64); s3 += __shfl(s3, src, 64);
  s4 += __shfl(s4, src, 64); s5 += __shfl(s5, src, 64);
  s6 += __shfl(s6, src, 64); s7 += __shfl(s7, src, 64);

  if (half == 0) {
    uint4 pv;
    pv.x = pack2(s0, s1); pv.y = pack2(s2, s3);
    pv.z = pack2(s4, s5); pv.w = pack2(s6, s7);
    if (mode == 0) {
      *(uint4*)((char*)out0 + (size_t)r * 512 + feat) = pv;
    } else {
      uint4 pr;
      pr.x = pack2(fmaxf(s0, 0.f), fmaxf(s1, 0.f));
      pr.y = pack2(fmaxf(s2, 0.f), fmaxf(s3, 0.f));
      pr.z = pack2(fmaxf(s4, 0.f), fmaxf(s5, 0.f));
      pr.w = pack2(fmaxf(s6, 0.f), fmaxf(s7, 0.f));
      *(uint4*)((char*)A1 + (size_t)r * 1024 + feat) = pr;          // relu(h3)
      *(uint4*)((char*)A1 + (size_t)r * 1024 + 512 + feat) = pv;    // h3
      *(uint4*)((char*)A2 + (size_t)r * 1536 + 1024 + feat) = pv;   // h3 tail
    }
  }
}

// -------------------------------------------------------------- launch ------
extern "C" void kernel_launch(void* const* d_in, const int* in_sizes, int n_in,
                              void* d_out, int out_size, void* d_ws, size_t ws_size,
                              hipStream_t stream) {
  const int* ei = (const int*)d_in[1];   // int inputs arrive as int32

  char* p = (char*)d_ws;
  auto carve = [&](size_t bytes) -> void* {
    void* r = (void*)p;
    p += (bytes + 255) & ~(size_t)255;
    return r;
  };
  unsigned* histRC  = (unsigned*)carve((size_t)NCH * NBIN * 4);
  u16*    chunkoff  = (u16*)carve((size_t)NCH * NBIN * 2);
  int*    cnt       = (int*)carve(NBIN * 4);
  int*    csr       = (int*)carve((size_t)NBIN * CAP * 4);
  float*  deg_inv   = (float*)carve(MPAD * 4);
  float*  bias1     = (float*)carve(512 * 4);
  float*  bf        = (float*)carve(64 * 4);
  u16* xb   = (u16*)carve((size_t)MPAD * 256 * 2);
  u16* w0t  = (u16*)carve(65536 * 2);
  u16* w1t  = (u16*)carve(65536 * 2);
  u16* w2t  = (u16*)carve(65536 * 2);
  u16* wc1t = (u16*)carve(262144 * 2);
  u16* wft  = (u16*)carve(49152 * 2);
  u16* tmp  = (u16*)carve((size_t)MPAD * 256 * 2);
  u16* h    = (u16*)carve((size_t)MPAD * 256 * 2);
  u16* cat1 = (u16*)carve((size_t)MPAD * 512 * 2);
  u16* cat2 = (u16*)carve((size_t)MPAD * 768 * 2);

  PP pp;
  pp.x = (const float*)d_in[0];
  pp.w0 = (const float*)d_in[2];
  pp.w1 = (const float*)d_in[4];
  pp.w2 = (const float*)d_in[6];
  pp.fcw0 = (const float*)d_in[8];
  pp.fcw1 = (const float*)d_in[10];
  pp.injw0 = (const float*)d_in[12];
  pp.injw1 = (const float*)d_in[14];
  pp.outw = (const float*)d_in[17];
  pp.fcb0 = (const float*)d_in[9];
  pp.injb0 = (const float*)d_in[13];
  pp.fcb1 = (const float*)d_in[11];
  pp.injb1 = (const float*)d_in[15];
  pp.alpha = (const float*)d_in[16];
  pp.outb = (const float*)d_in[18];
  pp.xb = xb; pp.w0t = w0t; pp.w1t = w1t; pp.w2t = w2t;
  pp.wc1t = wc1t; pp.wft = wft;
  pp.bias1 = bias1; pp.bf = bf;

  const float* mp_b0 = (const float*)d_in[3];
  const float* mp_b1 = (const float*)d_in[5];
  const float* mp_b2 = (const float*)d_in[7];
  float* out = (float*)d_out;

  edge_hist<<<NCH, 256, 0, stream>>>(ei, histRC);
  prep<<<PREP_BLOCKS, 256, 0, stream>>>(pp);
  col_scan<<<MPAD / 64, 64, 0, stream>>>(histRC, chunkoff, cnt, deg_inv);
  place_edges<<<NCH, 256, 0, stream>>>(ei, chunkoff, csr);

  dim3 gmp(MPAD / 64, 4), gfc(MPAD / 64, 8), go(MPAD / 64, 1);
  // MP layer 1..3: tmp = relu(h @ W + b) * deg_inv ; h' = CSR-aggregate(tmp)
  gemm64<256, true, true, false><<<gmp, 128, 0, stream>>>(xb, 256, w0t, mp_b0, deg_inv, tmp, nullptr, 256);
  aggregate<<<2500, 256, 0, stream>>>(tmp, cnt, csr, h, nullptr, nullptr, 0);
  gemm64<256, true, true, false><<<gmp, 128, 0, stream>>>(h, 256, w1t, mp_b1, deg_inv, tmp, nullptr, 256);
  aggregate<<<2500, 256, 0, stream>>>(tmp, cnt, csr, h, nullptr, nullptr, 0);
  gemm64<256, true, true, false><<<gmp, 128, 0, stream>>>(h, 256, w2t, mp_b2, deg_inv, tmp, nullptr, 256);
  aggregate<<<2500, 256, 0, stream>>>(tmp, cnt, csr, nullptr, cat1, cat2, 1);
  // FC1 (+inj0 fused, K=512) -> relu -> cat2[:, 0:512]
  gemm64<512, true, false, false><<<gfc, 128, 0, stream>>>(cat1, 512, wc1t, bias1, nullptr, cat2, nullptr, 768);
  // FOLDED: out = cat2 @ (Wcat2 @ out_w) + (bias2 @ out_w + out_b), fp32 store
  gemm64<768, false, false, true><<<go, 128, 0, stream>>>(cat2, 768, wft, bf, nullptr, nullptr, out, 64);
}

// Round 12
// 240.070 us; speedup vs baseline: 1.0434x; 1.0434x over previous
//
#include <hip/hip_runtime.h>

#define N_NODES 10000
#define N_EDGES 320000
#define MPAD 10112   // 158 * 64
#define NBIN 10048
#define CHUNK 2048
#define NCH 157      // ceil(E / CHUNK)
#define CAP 128      // fixed CSR row capacity (mean degree 32; 128 is ~17 sigma)
#define PREP_BLOCKS 512
#define PREP_TOT 1148480L

typedef unsigned short u16;
typedef short bf16x8 __attribute__((ext_vector_type(8)));
typedef float f32x4 __attribute__((ext_vector_type(4)));

__device__ __forceinline__ u16 f2b(float f) {
  unsigned u = __builtin_bit_cast(unsigned, f);
  unsigned r = u + 0x7fffu + ((u >> 16) & 1u);
  return (u16)(r >> 16);
}
__device__ __forceinline__ unsigned pack2(float a, float b) {
  return (unsigned)f2b(a) | ((unsigned)f2b(b) << 16);
}
__device__ __forceinline__ float blo(unsigned u) { return __builtin_bit_cast(float, u << 16); }
__device__ __forceinline__ float bhi(unsigned u) { return __builtin_bit_cast(float, u & 0xffff0000u); }

// ---------------------------------------------------------- param struct ----
struct PP {
  const float *x; const int *ei;
  const float *w0, *w1, *w2, *fcw0, *injw0, *fcw1, *injw1, *outw;
  const float *fcb0, *injb0, *fcb1, *injb1, *alpha, *outb;
  u16 *xb, *w0t, *w1t, *w2t, *wc1t, *wft;
  float *bias1, *bf;
  unsigned *histRC;
};

// ------------------------------------------------------- prep + edge_hist ---
// R10 measured-best structure: blocks 0..NCH-1 do packed per-chunk histograms
// (R low16 / C high16, 40KB LDS); blocks NCH.. grid-stride the prep items
// (x->bf16, W^T casts, fused Wcat1, FC2+out fold) CONCURRENTLY in the same
// dispatch (R11 split cost a gap + lost this overlap: 245->250us).
// Fold uses 4 partial accumulators + float4 loads (R11's ILP fix).
__global__ __launch_bounds__(256) void prep_hist(PP P) {
  __shared__ unsigned sh[NBIN];   // 40.2 KB packed
  const int tid = threadIdx.x, bid = blockIdx.x;
  const float alpha = P.alpha[0];

  if (bid < NCH) {  // ---- histogram chunk
    for (int i = tid; i < NBIN; i += 256) sh[i] = 0;
    __syncthreads();
    const int e0 = bid * CHUNK;
    for (int j = tid; j < CHUNK; j += 256) {
      int e = e0 + j;
      if (e < N_EDGES) {
        atomicAdd(&sh[P.ei[e]], 1u);                 // row (scatter dest)
        atomicAdd(&sh[P.ei[N_EDGES + e]], 65536u);   // col (deg source)
      }
    }
    __syncthreads();
    for (int i = tid; i < NBIN; i += 256)
      P.histRC[(size_t)bid * NBIN + i] = sh[i];
    return;
  }

  // ---- prep items, grid-stride
  const long stride = (long)PREP_BLOCKS * 256;
  for (long ii = (long)(bid - NCH) * 256 + tid; ii < PREP_TOT; ii += stride) {
    long i = ii;
    if (i < 640000L) {  // x -> bf16, 4 floats per item
      float4 v = ((const float4*)P.x)[i];
      uint2 o;
      o.x = pack2(v.x, v.y);
      o.y = pack2(v.z, v.w);
      *(uint2*)(P.xb + 4 * i) = o;
      continue;
    }
    i -= 640000L;
    if (i < 65536) { P.w0t[i] = f2b(P.w0[(i & 255) * 256 + (i >> 8)]); continue; }
    i -= 65536;
    if (i < 65536) { P.w1t[i] = f2b(P.w1[(i & 255) * 256 + (i >> 8)]); continue; }
    i -= 65536;
    if (i < 65536) { P.w2t[i] = f2b(P.w2[(i & 255) * 256 + (i >> 8)]); continue; }
    i -= 65536;
    if (i < 262144) {  // Wcat1^T [512 n][512 k]: k<256 -> alpha*fc_w0 ; else inj_w0
      int n = (int)(i >> 9), k = (int)(i & 511);
      float v = (k < 256) ? alpha * P.fcw0[k * 512 + n] : P.injw0[(k - 256) * 512 + n];
      P.wc1t[i] = f2b(v); continue;
    }
    i -= 262144;
    if (i < 49152) {   // Wf^T [64 n][768 k] = (Wcat2 @ out_w)^T, 4-acc ILP
      int n = (int)(i & 63), k = (int)(i >> 6);
      const float* fr = (k < 512) ? P.fcw1 + (size_t)k * 512
                                  : P.injw1 + (size_t)(k - 512) * 512;
      float a0 = 0.f, a1 = 0.f, a2 = 0.f, a3 = 0.f;
#pragma unroll 4
      for (int j = 0; j < 512; j += 4) {
        float4 f = *(const float4*)(fr + j);
        a0 += f.x * P.outw[(j + 0) * 64 + n];
        a1 += f.y * P.outw[(j + 1) * 64 + n];
        a2 += f.z * P.outw[(j + 2) * 64 + n];
        a3 += f.w * P.outw[(j + 3) * 64 + n];
      }
      float acc = (a0 + a1) + (a2 + a3);
      if (k < 512) acc *= alpha;
      P.wft[n * 768 + k] = f2b(acc);
      continue;
    }
    i -= 49152;
    if (i < 64) {      // bf = bias2 @ out_w + out_b (bias2 = alpha*fcb1+injb1)
      float acc = P.outb[i];
#pragma unroll 8
      for (int j = 0; j < 512; ++j)
        acc += (alpha * P.fcb1[j] + P.injb1[j]) * P.outw[j * 64 + i];
      P.bf[i] = acc;
      continue;
    }
    i -= 64;
    if (i < 512) { P.bias1[i] = alpha * P.fcb0[i] + P.injb0[i]; continue; }
  }
}

// ----------------------------------------------------------- CSR build ------
// Fixed-capacity CSR (row r = [r*CAP, r*CAP+cnt[r])) -> no global scan.
__global__ __launch_bounds__(64) void col_scan(const unsigned* __restrict__ histRC,
                                               u16* __restrict__ chunkoff,
                                               int* __restrict__ cnt,
                                               float* __restrict__ deg_inv) {
  int r = blockIdx.x * 64 + threadIdx.x;
  if (r >= MPAD) return;
  if (r >= NBIN) { deg_inv[r] = 1.0f; return; }
  unsigned run = 0;
#pragma unroll 8
  for (int ch = 0; ch < NCH; ++ch) {
    chunkoff[(size_t)ch * NBIN + r] = (u16)(run & 0xffffu);
    run += histRC[(size_t)ch * NBIN + r];
  }
  int cr = (int)(run & 0xffffu);
  int dg = (int)(run >> 16);
  cnt[r] = cr;
  deg_inv[r] = 1.0f / (float)(dg > 1 ? dg : 1);
}

// ------------------------------------------------------------- gemm tile ----
// 64x64 tile, TWO waves (128 thr): each wave computes a 32x64 strip
// (2x4 MFMA 16x16x32 frags). Proven R7-R11 body, factored as a device fn so
// place_gemm can share it on aliased LDS.
template<int K, bool RELU, bool SCALE, bool F32OUT>
__device__ __forceinline__ void gemm_tile(
    int m0, int n0,
    const u16* __restrict__ A, int lda,
    const u16* __restrict__ Bt,
    const float* __restrict__ bias,
    const float* __restrict__ scale,
    u16* __restrict__ Cb, float* __restrict__ Cf, int ldc,
    u16* As, u16* Bs, int tid)
{
  const int wave = tid >> 6;
  const int lane = tid & 63;
  const int wr = wave * 32;
  const int lm = lane & 15;
  const int koff = (lane >> 4) * 8;

  const int srow = tid >> 2;          // stages rows srow and srow+32
  const int scol = (tid & 3) * 16;    // 16 u16 per row = 2 int4
  const u16* Ag0 = A + (size_t)(m0 + srow) * lda + scol;
  const u16* Ag1 = A + (size_t)(m0 + srow + 32) * lda + scol;
  const u16* Bg0 = Bt + (size_t)(n0 + srow) * K + scol;
  const u16* Bg1 = Bt + (size_t)(n0 + srow + 32) * K + scol;
  u16* Asw0 = &As[srow * 72 + scol];
  u16* Asw1 = &As[(srow + 32) * 72 + scol];
  u16* Bsw0 = &Bs[srow * 72 + scol];
  u16* Bsw1 = &Bs[(srow + 32) * 72 + scol];

  f32x4 acc[2][4] = {};

  int4 pa0 = *(const int4*)(Ag0),     pa1 = *(const int4*)(Ag0 + 8);
  int4 pa2 = *(const int4*)(Ag1),     pa3 = *(const int4*)(Ag1 + 8);
  int4 pb0 = *(const int4*)(Bg0),     pb1 = *(const int4*)(Bg0 + 8);
  int4 pb2 = *(const int4*)(Bg1),     pb3 = *(const int4*)(Bg1 + 8);

#pragma unroll
  for (int kb = 0; kb < K; kb += 64) {
    __syncthreads();
    *(int4*)Asw0 = pa0; *(int4*)(Asw0 + 8) = pa1;
    *(int4*)Asw1 = pa2; *(int4*)(Asw1 + 8) = pa3;
    *(int4*)Bsw0 = pb0; *(int4*)(Bsw0 + 8) = pb1;
    *(int4*)Bsw1 = pb2; *(int4*)(Bsw1 + 8) = pb3;
    __syncthreads();
    if (kb + 64 < K) {
      pa0 = *(const int4*)(Ag0 + kb + 64); pa1 = *(const int4*)(Ag0 + kb + 72);
      pa2 = *(const int4*)(Ag1 + kb + 64); pa3 = *(const int4*)(Ag1 + kb + 72);
      pb0 = *(const int4*)(Bg0 + kb + 64); pb1 = *(const int4*)(Bg0 + kb + 72);
      pb2 = *(const int4*)(Bg1 + kb + 64); pb3 = *(const int4*)(Bg1 + kb + 72);
    }
#pragma unroll
    for (int ks = 0; ks < 2; ++ks) {
      bf16x8 af[2], bf[4];
#pragma unroll
      for (int mi = 0; mi < 2; ++mi)
        af[mi] = *(const bf16x8*)&As[(wr + mi * 16 + lm) * 72 + ks * 32 + koff];
#pragma unroll
      for (int ni = 0; ni < 4; ++ni)
        bf[ni] = *(const bf16x8*)&Bs[(ni * 16 + lm) * 72 + ks * 32 + koff];
#pragma unroll
      for (int mi = 0; mi < 2; ++mi)
#pragma unroll
        for (int ni = 0; ni < 4; ++ni)
          acc[mi][ni] = __builtin_amdgcn_mfma_f32_16x16x32_bf16(af[mi], bf[ni], acc[mi][ni], 0, 0, 0);
    }
  }

  const int q4 = (lane >> 4) * 4;
#pragma unroll
  for (int mi = 0; mi < 2; ++mi) {
#pragma unroll
    for (int ni = 0; ni < 4; ++ni) {
      const int gc = n0 + ni * 16 + lm;
      const float bv = bias[gc];
#pragma unroll
      for (int r = 0; r < 4; ++r) {
        const int gr = m0 + wr + mi * 16 + q4 + r;
        float v = acc[mi][ni][r] + bv;
        if (RELU) v = fmaxf(v, 0.f);
        if (SCALE) v *= scale[gr];
        if (F32OUT) {
          if (gr < N_NODES) Cf[(size_t)gr * ldc + gc] = v;
        } else {
          Cb[(size_t)gr * ldc + gc] = f2b(v);
        }
      }
    }
  }
}

template<int K, bool RELU, bool SCALE, bool F32OUT>
__global__ __launch_bounds__(128) void gemm64(
    const u16* __restrict__ A, int lda,
    const u16* __restrict__ Bt,
    const float* __restrict__ bias,
    const float* __restrict__ scale,
    u16* __restrict__ Cb, float* __restrict__ Cf, int ldc)
{
  __shared__ u16 As[64 * 72];
  __shared__ u16 Bs[64 * 72];
  gemm_tile<K, RELU, SCALE, F32OUT>(blockIdx.x * 64, blockIdx.y * 64,
                                    A, lda, Bt, bias, scale, Cb, Cf, ldc,
                                    As, Bs, threadIdx.x);
}

// ---------------------------------------------------- place + GEMM-1 fused --
// Blocks 0..NCH-1: edge placement (LDS cursor seeded from chunkoff — global
// state untouched, replay-safe). Blocks NCH..NCH+631: GEMM-1 tiles
// (tmp = relu(xb @ W0 + b0) * deg_inv). The two halves are mutually
// independent (both only need col_scan + prep outputs); fusing removes one
// dispatch gap and overlaps the gather-heavy place with MFMA work.
__global__ __launch_bounds__(128) void place_gemm(
    const int* __restrict__ ei, const u16* __restrict__ chunkoff,
    int* __restrict__ csr,
    const u16* __restrict__ xb, const u16* __restrict__ w0t,
    const float* __restrict__ mp_b0, const float* __restrict__ deg_inv,
    u16* __restrict__ tmp)
{
  __shared__ __align__(16) char smem[NBIN * 4];   // 40.2 KB, aliased
  const int bid = blockIdx.x, tid = threadIdx.x;

  if (bid < NCH) {  // ---- placement chunk
    int* cur = (int*)smem;
    const u16* co = chunkoff + (size_t)bid * NBIN;
    for (int i = tid; i < NBIN; i += 128) cur[i] = co[i];
    __syncthreads();
    const int e0 = bid * CHUNK;
    for (int j = 0; j < CHUNK; j += 128) {
      int e = e0 + j + tid;
      if (e < N_EDGES) {
        int r = ei[e];
        int c = ei[N_EDGES + e];
        int rank = atomicAdd(&cur[r], 1);   // LDS only; disjoint slots across chunks
        if (rank < CAP) csr[r * CAP + rank] = c;
      }
    }
    return;
  }

  // ---- GEMM-1 tile
  const int t = bid - NCH;                  // 0..631
  u16* As = (u16*)smem;                     // 9216 B
  u16* Bs = (u16*)(smem + 9216);            // 9216 B
  gemm_tile<256, true, true, false>((t % 158) * 64, (t / 158) * 64,
                                    xb, 256, w0t, mp_b0, deg_inv,
                                    tmp, nullptr, 256, As, Bs, tid);
}

// ----------------------------------------------------------- aggregate ------
// One WAVE per node; paired gather: half-wave per neighbor, uint4/lane,
// unroll 4 -> 8 neighbors in flight; cross-half __shfl reduce. (R10 proven)
__global__ __launch_bounds__(256) void aggregate(
    const u16* __restrict__ tmp, const int* __restrict__ cnt,
    const int* __restrict__ csr, u16* __restrict__ out0,
    u16* __restrict__ A1, u16* __restrict__ A2, int mode)
{
  const int wv = threadIdx.x >> 6;
  const int lane = threadIdx.x & 63;
  const int r = blockIdx.x * 4 + wv;          // grid = 2500 -> r in [0,10000)
  const int half = lane >> 5;
  const int q = lane & 31;
  const int beg = r * CAP, end = beg + cnt[r];
  const size_t feat = (size_t)q * 16;
  const char* tb = (const char*)tmp;

  float s0 = 0.f, s1 = 0.f, s2 = 0.f, s3 = 0.f, s4 = 0.f, s5 = 0.f, s6 = 0.f, s7 = 0.f;
  int i = beg;
  for (; i + 8 <= end; i += 8) {
    uint4 v[4];
#pragma unroll
    for (int j = 0; j < 4; ++j)
      v[j] = *(const uint4*)(tb + (size_t)csr[i + 2 * j + half] * 512 + feat);
#pragma unroll
    for (int j = 0; j < 4; ++j) {
      s0 += blo(v[j].x); s1 += bhi(v[j].x); s2 += blo(v[j].y); s3 += bhi(v[j].y);
      s4 += blo(v[j].z); s5 += bhi(v[j].z); s6 += blo(v[j].w); s7 += bhi(v[j].w);
    }
  }
  for (; i < end; i += 2) {
    int id = i + half;
    if (id < end) {
      uint4 v = *(const uint4*)(tb + (size_t)csr[id] * 512 + feat);
      s0 += blo(v.x); s1 += bhi(v.x); s2 += blo(v.y); s3 += bhi(v.y);
      s4 += blo(v.z); s5 += bhi(v.z); s6 += blo(v.w); s7 += bhi(v.w);
    }
  }
  const int src = lane ^ 32;
  s0 += __shfl(s0, src, 64); s1 += __shfl(s1, src, 64);
  s2 += __shfl(s2, src, 64); s3 += __shfl(s3, src, 64);
  s4 += __shfl(s4, src, 64); s5 += __shfl(s5, src, 64);
  s6 += __shfl(s6, src, 64); s7 += __shfl(s7, src, 64);

  if (half == 0) {
    uint4 pv;
    pv.x = pack2(s0, s1); pv.y = pack2(s2, s3);
    pv.z = pack2(s4, s5); pv.w = pack2(s6, s7);
    if (mode == 0) {
      *(uint4*)((char*)out0 + (size_t)r * 512 + feat) = pv;
    } else {
      uint4 pr;
      pr.x = pack2(fmaxf(s0, 0.f), fmaxf(s1, 0.f));
      pr.y = pack2(fmaxf(s2, 0.f), fmaxf(s3, 0.f));
      pr.z = pack2(fmaxf(s4, 0.f), fmaxf(s5, 0.f));
      pr.w = pack2(fmaxf(s6, 0.f), fmaxf(s7, 0.f));
      *(uint4*)((char*)A1 + (size_t)r * 1024 + feat) = pr;          // relu(h3)
      *(uint4*)((char*)A1 + (size_t)r * 1024 + 512 + feat) = pv;    // h3
      *(uint4*)((char*)A2 + (size_t)r * 1536 + 1024 + feat) = pv;   // h3 tail
    }
  }
}

// -------------------------------------------------------------- launch ------
extern "C" void kernel_launch(void* const* d_in, const int* in_sizes, int n_in,
                              void* d_out, int out_size, void* d_ws, size_t ws_size,
                              hipStream_t stream) {
  const int* ei = (const int*)d_in[1];   // int inputs arrive as int32

  char* p = (char*)d_ws;
  auto carve = [&](size_t bytes) -> void* {
    void* r = (void*)p;
    p += (bytes + 255) & ~(size_t)255;
    return r;
  };
  unsigned* histRC  = (unsigned*)carve((size_t)NCH * NBIN * 4);
  u16*    chunkoff  = (u16*)carve((size_t)NCH * NBIN * 2);
  int*    cnt       = (int*)carve(NBIN * 4);
  int*    csr       = (int*)carve((size_t)NBIN * CAP * 4);
  float*  deg_inv   = (float*)carve(MPAD * 4);
  float*  bias1     = (float*)carve(512 * 4);
  float*  bf        = (float*)carve(64 * 4);
  u16* xb   = (u16*)carve((size_t)MPAD * 256 * 2);
  u16* w0t  = (u16*)carve(65536 * 2);
  u16* w1t  = (u16*)carve(65536 * 2);
  u16* w2t  = (u16*)carve(65536 * 2);
  u16* wc1t = (u16*)carve(262144 * 2);
  u16* wft  = (u16*)carve(49152 * 2);
  u16* tmp  = (u16*)carve((size_t)MPAD * 256 * 2);
  u16* h    = (u16*)carve((size_t)MPAD * 256 * 2);
  u16* cat1 = (u16*)carve((size_t)MPAD * 512 * 2);
  u16* cat2 = (u16*)carve((size_t)MPAD * 768 * 2);

  PP pp;
  pp.x = (const float*)d_in[0];
  pp.ei = ei;
  pp.w0 = (const float*)d_in[2];
  pp.w1 = (const float*)d_in[4];
  pp.w2 = (const float*)d_in[6];
  pp.fcw0 = (const float*)d_in[8];
  pp.fcw1 = (const float*)d_in[10];
  pp.injw0 = (const float*)d_in[12];
  pp.injw1 = (const float*)d_in[14];
  pp.outw = (const float*)d_in[17];
  pp.fcb0 = (const float*)d_in[9];
  pp.injb0 = (const float*)d_in[13];
  pp.fcb1 = (const float*)d_in[11];
  pp.injb1 = (const float*)d_in[15];
  pp.alpha = (const float*)d_in[16];
  pp.outb = (const float*)d_in[18];
  pp.xb = xb; pp.w0t = w0t; pp.w1t = w1t; pp.w2t = w2t;
  pp.wc1t = wc1t; pp.wft = wft;
  pp.bias1 = bias1; pp.bf = bf;
  pp.histRC = histRC;

  const float* mp_b0 = (const float*)d_in[3];
  const float* mp_b1 = (const float*)d_in[5];
  const float* mp_b2 = (const float*)d_in[7];
  float* out = (float*)d_out;

  prep_hist<<<NCH + PREP_BLOCKS, 256, 0, stream>>>(pp);
  col_scan<<<MPAD / 64, 64, 0, stream>>>(histRC, chunkoff, cnt, deg_inv);
  // fused: edge placement + GEMM-1 (mutually independent after col_scan)
  place_gemm<<<NCH + 632, 128, 0, stream>>>(ei, chunkoff, csr,
                                            xb, w0t, mp_b0, deg_inv, tmp);

  dim3 gmp(MPAD / 64, 4), gfc(MPAD / 64, 8), go(MPAD / 64, 1);
  aggregate<<<2500, 256, 0, stream>>>(tmp, cnt, csr, h, nullptr, nullptr, 0);
  gemm64<256, true, true, false><<<gmp, 128, 0, stream>>>(h, 256, w1t, mp_b1, deg_inv, tmp, nullptr, 256);
  aggregate<<<2500, 256, 0, stream>>>(tmp, cnt, csr, h, nullptr, nullptr, 0);
  gemm64<256, true, true, false><<<gmp, 128, 0, stream>>>(h, 256, w2t, mp_b2, deg_inv, tmp, nullptr, 256);
  aggregate<<<2500, 256, 0, stream>>>(tmp, cnt, csr, nullptr, cat1, cat2, 1);
  // FC1 (+inj0 fused, K=512) -> relu -> cat2[:, 0:512]
  gemm64<512, true, false, false><<<gfc, 128, 0, stream>>>(cat1, 512, wc1t, bias1, nullptr, cat2, nullptr, 768);
  // FOLDED: out = cat2 @ (Wcat2 @ out_w) + (bias2 @ out_w + out_b), fp32 store
  gemm64<768, false, false, true><<<go, 128, 0, stream>>>(cat2, 768, wft, bf, nullptr, nullptr, out, 64);
}

// Round 13
// 234.328 us; speedup vs baseline: 1.0690x; 1.0245x over previous
//
#include <hip/hip_runtime.h>

#define N_NODES 10000
#define N_EDGES 320000
#define MPAD 10112   // 158 * 64
#define NBIN 10048
#define CAP 128      // fixed CSR row capacity (mean degree 32; >CAP is ~17 sigma)
#define EBLKS 157    // edge-placement blocks (2048 edges each)
#define PREP_BLOCKS 512
#define PREP_TOT 1148480L

typedef unsigned short u16;
typedef short bf16x8 __attribute__((ext_vector_type(8)));
typedef float f32x4 __attribute__((ext_vector_type(4)));

__device__ __forceinline__ u16 f2b(float f) {
  unsigned u = __builtin_bit_cast(unsigned, f);
  unsigned r = u + 0x7fffu + ((u >> 16) & 1u);
  return (u16)(r >> 16);
}
__device__ __forceinline__ unsigned pack2(float a, float b) {
  return (unsigned)f2b(a) | ((unsigned)f2b(b) << 16);
}
__device__ __forceinline__ float blo(unsigned u) { return __builtin_bit_cast(float, u << 16); }
__device__ __forceinline__ float bhi(unsigned u) { return __builtin_bit_cast(float, u & 0xffff0000u); }

// ---------------------------------------------------------- param struct ----
struct PP {
  const float *x; const int *ei;
  const float *w0, *w1, *w2, *fcw0, *injw0, *fcw1, *injw1, *outw;
  const float *fcb0, *injb0, *fcb1, *injb1, *alpha, *outb;
  u16 *xb, *w0t, *w1t, *w2t, *wc1t, *wft;
  float *bias1, *bf;
  int *cursor, *deg, *csr;
};

// ------------------------------------------------------- prep + placement ---
// R13: the 3-stage deterministic CSR (hist 12.6MB + col_scan strided scan +
// LDS-cursor place) is replaced by GUARDED direct atomic placement: cursor &
// deg are memset-zeroed IN-GRAPH, so timed replays are deterministic; the
// pos<CAP guard makes OOB impossible (R3's corruption came from unguarded
// cursors). Blocks 0..EBLKS-1 place edges; blocks EBLKS.. do prep items.
// No LDS anywhere -> full occupancy for both halves.
__global__ __launch_bounds__(256) void prep_place(PP P) {
  const int tid = threadIdx.x, bid = blockIdx.x;

  if (bid < EBLKS) {  // ---- edge placement + degree count
    const int e0 = bid * 2048;
#pragma unroll
    for (int j = 0; j < 2048; j += 256) {
      int e = e0 + j + tid;
      if (e < N_EDGES) {
        int r = P.ei[e];
        int c = P.ei[N_EDGES + e];
        int pos = atomicAdd(&P.cursor[r], 1);
        if (pos < CAP) P.csr[r * CAP + pos] = c;   // guarded: no OOB ever
        atomicAdd(&P.deg[c], 1);                   // reference deg = segsum(col)
      }
    }
    return;
  }

  // ---- prep items, grid-stride
  const float alpha = P.alpha[0];
  const long stride = (long)PREP_BLOCKS * 256;
  for (long ii = (long)(bid - EBLKS) * 256 + tid; ii < PREP_TOT; ii += stride) {
    long i = ii;
    if (i < 640000L) {  // x -> bf16, 4 floats per item
      float4 v = ((const float4*)P.x)[i];
      uint2 o;
      o.x = pack2(v.x, v.y);
      o.y = pack2(v.z, v.w);
      *(uint2*)(P.xb + 4 * i) = o;
      continue;
    }
    i -= 640000L;
    if (i < 65536) { P.w0t[i] = f2b(P.w0[(i & 255) * 256 + (i >> 8)]); continue; }
    i -= 65536;
    if (i < 65536) { P.w1t[i] = f2b(P.w1[(i & 255) * 256 + (i >> 8)]); continue; }
    i -= 65536;
    if (i < 65536) { P.w2t[i] = f2b(P.w2[(i & 255) * 256 + (i >> 8)]); continue; }
    i -= 65536;
    if (i < 262144) {  // Wcat1^T [512 n][512 k]: k<256 -> alpha*fc_w0 ; else inj_w0
      int n = (int)(i >> 9), k = (int)(i & 511);
      float v = (k < 256) ? alpha * P.fcw0[k * 512 + n] : P.injw0[(k - 256) * 512 + n];
      P.wc1t[i] = f2b(v); continue;
    }
    i -= 262144;
    if (i < 49152) {   // Wf^T [64 n][768 k] = (Wcat2 @ out_w)^T, 4-acc ILP
      int n = (int)(i & 63), k = (int)(i >> 6);
      const float* fr = (k < 512) ? P.fcw1 + (size_t)k * 512
                                  : P.injw1 + (size_t)(k - 512) * 512;
      float a0 = 0.f, a1 = 0.f, a2 = 0.f, a3 = 0.f;
#pragma unroll 4
      for (int j = 0; j < 512; j += 4) {
        float4 f = *(const float4*)(fr + j);
        a0 += f.x * P.outw[(j + 0) * 64 + n];
        a1 += f.y * P.outw[(j + 1) * 64 + n];
        a2 += f.z * P.outw[(j + 2) * 64 + n];
        a3 += f.w * P.outw[(j + 3) * 64 + n];
      }
      float acc = (a0 + a1) + (a2 + a3);
      if (k < 512) acc *= alpha;
      P.wft[n * 768 + k] = f2b(acc);
      continue;
    }
    i -= 49152;
    if (i < 64) {      // bf = bias2 @ out_w + out_b (bias2 = alpha*fcb1+injb1)
      float acc = P.outb[i];
#pragma unroll 8
      for (int j = 0; j < 512; ++j)
        acc += (alpha * P.fcb1[j] + P.injb1[j]) * P.outw[j * 64 + i];
      P.bf[i] = acc;
      continue;
    }
    i -= 64;
    if (i < 512) { P.bias1[i] = alpha * P.fcb0[i] + P.injb0[i]; continue; }
  }
}

// ---------------------------------------------------------------- GEMM ------
// 64x64 tile, TWO waves per block (128 thr): each wave a 32x64 strip
// (2x4 MFMA 16x16x32 frags). Proven R7-R12 body. SCALE now reads deg[] and
// divides inline (1.0f/max(deg,1) — same fp32 math as the old deg_inv buf).
template<int K, bool RELU, bool SCALE, bool F32OUT>
__global__ __launch_bounds__(128) void gemm64(
    const u16* __restrict__ A, int lda,
    const u16* __restrict__ Bt,
    const float* __restrict__ bias,
    const int* __restrict__ deg,
    u16* __restrict__ Cb, float* __restrict__ Cf, int ldc)
{
  __shared__ u16 As[64 * 72];
  __shared__ u16 Bs[64 * 72];
  const int tid = threadIdx.x;
  const int m0 = blockIdx.x * 64;
  const int n0 = blockIdx.y * 64;
  const int wave = tid >> 6;
  const int lane = tid & 63;
  const int wr = wave * 32;
  const int lm = lane & 15;
  const int koff = (lane >> 4) * 8;

  const int srow = tid >> 2;          // stages rows srow and srow+32
  const int scol = (tid & 3) * 16;    // 16 u16 per row = 2 int4
  const u16* Ag0 = A + (size_t)(m0 + srow) * lda + scol;
  const u16* Ag1 = A + (size_t)(m0 + srow + 32) * lda + scol;
  const u16* Bg0 = Bt + (size_t)(n0 + srow) * K + scol;
  const u16* Bg1 = Bt + (size_t)(n0 + srow + 32) * K + scol;
  u16* Asw0 = &As[srow * 72 + scol];
  u16* Asw1 = &As[(srow + 32) * 72 + scol];
  u16* Bsw0 = &Bs[srow * 72 + scol];
  u16* Bsw1 = &Bs[(srow + 32) * 72 + scol];

  f32x4 acc[2][4] = {};

  int4 pa0 = *(const int4*)(Ag0),     pa1 = *(const int4*)(Ag0 + 8);
  int4 pa2 = *(const int4*)(Ag1),     pa3 = *(const int4*)(Ag1 + 8);
  int4 pb0 = *(const int4*)(Bg0),     pb1 = *(const int4*)(Bg0 + 8);
  int4 pb2 = *(const int4*)(Bg1),     pb3 = *(const int4*)(Bg1 + 8);

#pragma unroll
  for (int kb = 0; kb < K; kb += 64) {
    __syncthreads();
    *(int4*)Asw0 = pa0; *(int4*)(Asw0 + 8) = pa1;
    *(int4*)Asw1 = pa2; *(int4*)(Asw1 + 8) = pa3;
    *(int4*)Bsw0 = pb0; *(int4*)(Bsw0 + 8) = pb1;
    *(int4*)Bsw1 = pb2; *(int4*)(Bsw1 + 8) = pb3;
    __syncthreads();
    if (kb + 64 < K) {
      pa0 = *(const int4*)(Ag0 + kb + 64); pa1 = *(const int4*)(Ag0 + kb + 72);
      pa2 = *(const int4*)(Ag1 + kb + 64); pa3 = *(const int4*)(Ag1 + kb + 72);
      pb0 = *(const int4*)(Bg0 + kb + 64); pb1 = *(const int4*)(Bg0 + kb + 72);
      pb2 = *(const int4*)(Bg1 + kb + 64); pb3 = *(const int4*)(Bg1 + kb + 72);
    }
#pragma unroll
    for (int ks = 0; ks < 2; ++ks) {
      bf16x8 af[2], bf[4];
#pragma unroll
      for (int mi = 0; mi < 2; ++mi)
        af[mi] = *(const bf16x8*)&As[(wr + mi * 16 + lm) * 72 + ks * 32 + koff];
#pragma unroll
      for (int ni = 0; ni < 4; ++ni)
        bf[ni] = *(const bf16x8*)&Bs[(ni * 16 + lm) * 72 + ks * 32 + koff];
#pragma unroll
      for (int mi = 0; mi < 2; ++mi)
#pragma unroll
        for (int ni = 0; ni < 4; ++ni)
          acc[mi][ni] = __builtin_amdgcn_mfma_f32_16x16x32_bf16(af[mi], bf[ni], acc[mi][ni], 0, 0, 0);
    }
  }

  const int q4 = (lane >> 4) * 4;
#pragma unroll
  for (int mi = 0; mi < 2; ++mi) {
#pragma unroll
    for (int ni = 0; ni < 4; ++ni) {
      const int gc = n0 + ni * 16 + lm;
      const float bv = bias[gc];
#pragma unroll
      for (int r = 0; r < 4; ++r) {
        const int gr = m0 + wr + mi * 16 + q4 + r;
        float v = acc[mi][ni][r] + bv;
        if (RELU) v = fmaxf(v, 0.f);
        if (SCALE) v *= 1.0f / fmaxf((float)deg[gr], 1.0f);
        if (F32OUT) {
          if (gr < N_NODES) Cf[(size_t)gr * ldc + gc] = v;
        } else {
          Cb[(size_t)gr * ldc + gc] = f2b(v);
        }
      }
    }
  }
}

// ----------------------------------------------------- fold GEMM (split A) --
// out = [relu1 | h3] @ Wf + bf. A columns 0..511 from relu1 (10048x512);
// columns 512..767 are h3 = cat1 cols 256..511. Each 16-u16 staged segment
// lies entirely on one side of the split (kb multiple of 64, scol<64), so a
// per-segment pointer select is exact. Kills the cat2 buffer entirely.
__global__ __launch_bounds__(128) void gemm_fold(
    const u16* __restrict__ Ar,    // relu1, lda 512
    const u16* __restrict__ Ah,    // cat1 + 256 (h3 half), lda 512
    const u16* __restrict__ Bt,    // wft, K=768
    const float* __restrict__ bias,
    float* __restrict__ Cf)        // out, ldc 64
{
  const int K = 768;
  __shared__ u16 As[64 * 72];
  __shared__ u16 Bs[64 * 72];
  const int tid = threadIdx.x;
  const int m0 = blockIdx.x * 64;
  const int n0 = 0;
  const int wave = tid >> 6;
  const int lane = tid & 63;
  const int wr = wave * 32;
  const int lm = lane & 15;
  const int koff = (lane >> 4) * 8;

  const int srow = tid >> 2;
  const int scol = (tid & 3) * 16;
  const int ar0 = m0 + srow, ar1 = m0 + srow + 32;
  auto aptr = [&](int row, int col) -> const u16* {
    return (col < 512) ? Ar + (size_t)row * 512 + col
                       : Ah + (size_t)row * 512 + (col - 512);
  };
  const u16* Bg0 = Bt + (size_t)(n0 + srow) * K + scol;
  const u16* Bg1 = Bt + (size_t)(n0 + srow + 32) * K + scol;
  u16* Asw0 = &As[srow * 72 + scol];
  u16* Asw1 = &As[(srow + 32) * 72 + scol];
  u16* Bsw0 = &Bs[srow * 72 + scol];
  u16* Bsw1 = &Bs[(srow + 32) * 72 + scol];

  f32x4 acc[2][4] = {};

  int4 pa0 = *(const int4*)aptr(ar0, scol);
  int4 pa1 = *(const int4*)aptr(ar0, scol + 8);
  int4 pa2 = *(const int4*)aptr(ar1, scol);
  int4 pa3 = *(const int4*)aptr(ar1, scol + 8);
  int4 pb0 = *(const int4*)(Bg0), pb1 = *(const int4*)(Bg0 + 8);
  int4 pb2 = *(const int4*)(Bg1), pb3 = *(const int4*)(Bg1 + 8);

#pragma unroll
  for (int kb = 0; kb < K; kb += 64) {
    __syncthreads();
    *(int4*)Asw0 = pa0; *(int4*)(Asw0 + 8) = pa1;
    *(int4*)Asw1 = pa2; *(int4*)(Asw1 + 8) = pa3;
    *(int4*)Bsw0 = pb0; *(int4*)(Bsw0 + 8) = pb1;
    *(int4*)Bsw1 = pb2; *(int4*)(Bsw1 + 8) = pb3;
    __syncthreads();
    if (kb + 64 < K) {
      int c = kb + 64 + scol;
      pa0 = *(const int4*)aptr(ar0, c);
      pa1 = *(const int4*)aptr(ar0, c + 8);
      pa2 = *(const int4*)aptr(ar1, c);
      pa3 = *(const int4*)aptr(ar1, c + 8);
      pb0 = *(const int4*)(Bg0 + kb + 64); pb1 = *(const int4*)(Bg0 + kb + 72);
      pb2 = *(const int4*)(Bg1 + kb + 64); pb3 = *(const int4*)(Bg1 + kb + 72);
    }
#pragma unroll
    for (int ks = 0; ks < 2; ++ks) {
      bf16x8 af[2], bf[4];
#pragma unroll
      for (int mi = 0; mi < 2; ++mi)
        af[mi] = *(const bf16x8*)&As[(wr + mi * 16 + lm) * 72 + ks * 32 + koff];
#pragma unroll
      for (int ni = 0; ni < 4; ++ni)
        bf[ni] = *(const bf16x8*)&Bs[(ni * 16 + lm) * 72 + ks * 32 + koff];
#pragma unroll
      for (int mi = 0; mi < 2; ++mi)
#pragma unroll
        for (int ni = 0; ni < 4; ++ni)
          acc[mi][ni] = __builtin_amdgcn_mfma_f32_16x16x32_bf16(af[mi], bf[ni], acc[mi][ni], 0, 0, 0);
    }
  }

  const int q4 = (lane >> 4) * 4;
#pragma unroll
  for (int mi = 0; mi < 2; ++mi) {
#pragma unroll
    for (int ni = 0; ni < 4; ++ni) {
      const int gc = ni * 16 + lm;
      const float bv = bias[gc];
#pragma unroll
      for (int r = 0; r < 4; ++r) {
        const int gr = m0 + wr + mi * 16 + q4 + r;
        if (gr < N_NODES) Cf[(size_t)gr * 64 + gc] = acc[mi][ni][r] + bv;
      }
    }
  }
}

// ----------------------------------------------------------- aggregate ------
// One WAVE per node; paired gather: half-wave per neighbor, uint4/lane,
// unroll 4 -> 8 neighbors in flight; cross-half __shfl reduce. Fixed-CAP CSR;
// cnt = cursor (clamped to CAP for replay-safety of the guard).
__global__ __launch_bounds__(256) void aggregate(
    const u16* __restrict__ tmp, const int* __restrict__ cnt,
    const int* __restrict__ csr, u16* __restrict__ out0,
    u16* __restrict__ A1, int mode)
{
  const int wv = threadIdx.x >> 6;
  const int lane = threadIdx.x & 63;
  const int r = blockIdx.x * 4 + wv;          // grid = 2500 -> r in [0,10000)
  const int half = lane >> 5;
  const int q = lane & 31;
  int n = cnt[r]; if (n > CAP) n = CAP;
  const int beg = r * CAP, end = beg + n;
  const size_t feat = (size_t)q * 16;
  const char* tb = (const char*)tmp;

  float s0 = 0.f, s1 = 0.f, s2 = 0.f, s3 = 0.f, s4 = 0.f, s5 = 0.f, s6 = 0.f, s7 = 0.f;
  int i = beg;
  for (; i + 8 <= end; i += 8) {
    uint4 v[4];
#pragma unroll
    for (int j = 0; j < 4; ++j)
      v[j] = *(const uint4*)(tb + (size_t)csr[i + 2 * j + half] * 512 + feat);
#pragma unroll
    for (int j = 0; j < 4; ++j) {
      s0 += blo(v[j].x); s1 += bhi(v[j].x); s2 += blo(v[j].y); s3 += bhi(v[j].y);
      s4 += blo(v[j].z); s5 += bhi(v[j].z); s6 += blo(v[j].w); s7 += bhi(v[j].w);
    }
  }
  for (; i < end; i += 2) {
    int id = i + half;
    if (id < end) {
      uint4 v = *(const uint4*)(tb + (size_t)csr[id] * 512 + feat);
      s0 += blo(v.x); s1 += bhi(v.x); s2 += blo(v.y); s3 += bhi(v.y);
      s4 += blo(v.z); s5 += bhi(v.z); s6 += blo(v.w); s7 += bhi(v.w);
    }
  }
  const int src = lane ^ 32;
  s0 += __shfl(s0, src, 64); s1 += __shfl(s1, src, 64);
  s2 += __shfl(s2, src, 64); s3 += __shfl(s3, src, 64);
  s4 += __shfl(s4, src, 64); s5 += __shfl(s5, src, 64);
  s6 += __shfl(s6, src, 64); s7 += __shfl(s7, src, 64);

  if (half == 0) {
    uint4 pv;
    pv.x = pack2(s0, s1); pv.y = pack2(s2, s3);
    pv.z = pack2(s4, s5); pv.w = pack2(s6, s7);
    if (mode == 0) {
      *(uint4*)((char*)out0 + (size_t)r * 512 + feat) = pv;
    } else {
      uint4 pr;
      pr.x = pack2(fmaxf(s0, 0.f), fmaxf(s1, 0.f));
      pr.y = pack2(fmaxf(s2, 0.f), fmaxf(s3, 0.f));
      pr.z = pack2(fmaxf(s4, 0.f), fmaxf(s5, 0.f));
      pr.w = pack2(fmaxf(s6, 0.f), fmaxf(s7, 0.f));
      *(uint4*)((char*)A1 + (size_t)r * 1024 + feat) = pr;          // relu(h3)
      *(uint4*)((char*)A1 + (size_t)r * 1024 + 512 + feat) = pv;    // h3
    }
  }
}

// -------------------------------------------------------------- launch ------
extern "C" void kernel_launch(void* const* d_in, const int* in_sizes, int n_in,
                              void* d_out, int out_size, void* d_ws, size_t ws_size,
                              hipStream_t stream) {
  const int* ei = (const int*)d_in[1];   // int inputs arrive as int32

  char* p = (char*)d_ws;
  auto carve = [&](size_t bytes) -> void* {
    void* r = (void*)p;
    p += (bytes + 255) & ~(size_t)255;
    return r;
  };
  int*   deg     = (int*)carve(MPAD * 4);     // 40448 B (256-mult) — adjacent
  int*   cursor  = (int*)carve(NBIN * 4);     // 40192 B (256-mult) — to deg
  int*   csr     = (int*)carve((size_t)NBIN * CAP * 4);
  float* bias1   = (float*)carve(512 * 4);
  float* bf      = (float*)carve(64 * 4);
  u16* xb    = (u16*)carve((size_t)MPAD * 256 * 2);
  u16* w0t   = (u16*)carve(65536 * 2);
  u16* w1t   = (u16*)carve(65536 * 2);
  u16* w2t   = (u16*)carve(65536 * 2);
  u16* wc1t  = (u16*)carve(262144 * 2);
  u16* wft   = (u16*)carve(49152 * 2);
  u16* tmp   = (u16*)carve((size_t)MPAD * 256 * 2);
  u16* h     = (u16*)carve((size_t)MPAD * 256 * 2);
  u16* cat1  = (u16*)carve((size_t)MPAD * 512 * 2);   // [relu(h3)|h3], 1024B rows
  u16* relu1 = (u16*)carve((size_t)MPAD * 512 * 2);   // relu(FC1 out)

  PP pp;
  pp.x = (const float*)d_in[0];
  pp.ei = ei;
  pp.w0 = (const float*)d_in[2];
  pp.w1 = (const float*)d_in[4];
  pp.w2 = (const float*)d_in[6];
  pp.fcw0 = (const float*)d_in[8];
  pp.fcw1 = (const float*)d_in[10];
  pp.injw0 = (const float*)d_in[12];
  pp.injw1 = (const float*)d_in[14];
  pp.outw = (const float*)d_in[17];
  pp.fcb0 = (const float*)d_in[9];
  pp.injb0 = (const float*)d_in[13];
  pp.fcb1 = (const float*)d_in[11];
  pp.injb1 = (const float*)d_in[15];
  pp.alpha = (const float*)d_in[16];
  pp.outb = (const float*)d_in[18];
  pp.xb = xb; pp.w0t = w0t; pp.w1t = w1t; pp.w2t = w2t;
  pp.wc1t = wc1t; pp.wft = wft;
  pp.bias1 = bias1; pp.bf = bf;
  pp.cursor = cursor; pp.deg = deg; pp.csr = csr;

  const float* mp_b0 = (const float*)d_in[3];
  const float* mp_b1 = (const float*)d_in[5];
  const float* mp_b2 = (const float*)d_in[7];
  float* out = (float*)d_out;

  // deg (MPAD) + cursor (NBIN) are adjacent: one in-graph memset -> timed
  // replays reset atomic state deterministically.
  hipMemsetAsync(deg, 0, (size_t)(MPAD + NBIN) * 4, stream);
  prep_place<<<EBLKS + PREP_BLOCKS, 256, 0, stream>>>(pp);

  dim3 gmp(MPAD / 64, 4), gfc(MPAD / 64, 8), go(MPAD / 64, 1);
  // MP layer 1..3: tmp = relu(h @ W + b) / deg ; h' = CSR-aggregate(tmp)
  gemm64<256, true, true, false><<<gmp, 128, 0, stream>>>(xb, 256, w0t, mp_b0, deg, tmp, nullptr, 256);
  aggregate<<<2500, 256, 0, stream>>>(tmp, cursor, csr, h, nullptr, 0);
  gemm64<256, true, true, false><<<gmp, 128, 0, stream>>>(h, 256, w1t, mp_b1, deg, tmp, nullptr, 256);
  aggregate<<<2500, 256, 0, stream>>>(tmp, cursor, csr, h, nullptr, 0);
  gemm64<256, true, true, false><<<gmp, 128, 0, stream>>>(h, 256, w2t, mp_b2, deg, tmp, nullptr, 256);
  aggregate<<<2500, 256, 0, stream>>>(tmp, cursor, csr, nullptr, cat1, 1);
  // FC1 (+inj0 fused, K=512): cat1=[relu(h3)|h3] -> relu -> relu1 (dense)
  gemm64<512, true, false, false><<<gfc, 128, 0, stream>>>(cat1, 512, wc1t, bias1, nullptr, relu1, nullptr, 512);
  // FOLDED final: out = [relu1 | h3] @ (Wcat2 @ out_w) + bf, fp32 store
  gemm_fold<<<go, 128, 0, stream>>>(relu1, cat1 + 256, wft, bf, out);
}